// Round 2
// baseline (88.284 us; speedup 1.0000x reference)
//
#include <hip/hip_runtime.h>

// out[i] = sum_k a[k] * tanh(5*(x[i]+b[k])), k=0..6
// tanh(z) = 1 - 2/(exp(2z)+1)
// exp(10*(x+b_k)) = exp2(SC*x) * exp2(SC*b_k) = E * c_k,  SC = 10*log2(e)
// => out = suma + sum_k (-2*a_k) * rcp(E*c_k + 1)
// ONE exp2 per element (shared across all 7 terms) + 7 rcp.
//
// R2 = R1 with the nontemporal builtins applied to a native clang vector
// type (ext_vector_type(4)) instead of HIP_vector_type float4, which the
// builtin rejects.
//  - weights: 4 vector loads (float4 x3 + float2) instead of 14 scalar loads
//  - 8 elements/thread as two coalesced float4 streams (i and i+half):
//    8 independent exp2 + 8 independent rcp-chains -> 2x trans-pipe ILP
//  - nontemporal load/store (pure streaming, zero reuse)

#define K_TERMS 7

typedef float f32x4 __attribute__((ext_vector_type(4)));

__device__ __forceinline__ float fast_exp2(float x) { return __builtin_amdgcn_exp2f(x); }
__device__ __forceinline__ float fast_rcp(float x)  { return __builtin_amdgcn_rcpf(x); }

__global__ __launch_bounds__(256)
void quantizationLayer_49563922596433_kernel(const float* __restrict__ x,
                                             const float* __restrict__ w,
                                             float* __restrict__ out,
                                             int half, int n4) {
    const float SC = 14.4269504088896f; // 10 * log2(e)

    // ---- weight-derived constants: 4 vector loads, all uniform ----
    f32x4 w0 = ((const f32x4*)w)[0];   // a0,b0,a1,b1
    f32x4 w1 = ((const f32x4*)w)[1];   // a2,b2,a3,b3
    f32x4 w2 = ((const f32x4*)w)[2];   // a4,b4,a5,b5
    float w3a = w[12], w3b = w[13];    // a6,b6

    float av[K_TERMS] = {w0.x, w0.z, w1.x, w1.z, w2.x, w2.z, w3a};
    float bv[K_TERMS] = {w0.y, w0.w, w1.y, w1.w, w2.y, w2.w, w3b};

    float suma = 0.f;
    float ck[K_TERMS], na2[K_TERMS];
#pragma unroll
    for (int k = 0; k < K_TERMS; ++k) {
        suma  += av[k];
        ck[k]  = fast_exp2(SC * bv[k]);
        na2[k] = -2.f * av[k];
    }

    int i = blockIdx.x * blockDim.x + threadIdx.x;
    if (i >= half) return;

    const f32x4* x4 = (const f32x4*)x;
    f32x4*       o4 = (f32x4*)out;

    // two coalesced streams: vec4 #i and vec4 #(i+half)
    f32x4 va = __builtin_nontemporal_load(x4 + i);
    f32x4 vb = __builtin_nontemporal_load(x4 + i + half);

    float in[8] = {va.x, va.y, va.z, va.w, vb.x, vb.y, vb.z, vb.w};

    // all 8 exp2 first (independent, fills the quarter-rate trans pipe)
    float E[8];
#pragma unroll
    for (int j = 0; j < 8; ++j) E[j] = fast_exp2(in[j] * SC);

    float o[8];
#pragma unroll
    for (int j = 0; j < 8; ++j) {
        float acc = suma;
#pragma unroll
        for (int k = 0; k < K_TERMS; ++k) {
            float d = fmaf(E[j], ck[k], 1.f);   // E*c_k + 1
            acc = fmaf(na2[k], fast_rcp(d), acc);
        }
        o[j] = acc;
    }

    f32x4 oa = {o[0], o[1], o[2], o[3]};
    f32x4 ob = {o[4], o[5], o[6], o[7]};
    __builtin_nontemporal_store(oa, o4 + i);
    __builtin_nontemporal_store(ob, o4 + i + half);

    // odd-n4 tail (dead for 2048x4096, kept for safety)
    if (i == 0 && (n4 & 1)) {
        f32x4 vt = x4[n4 - 1];
        float it[4] = {vt.x, vt.y, vt.z, vt.w};
        float ot[4];
#pragma unroll
        for (int j = 0; j < 4; ++j) {
            float Et  = fast_exp2(it[j] * SC);
            float acc = suma;
#pragma unroll
            for (int k = 0; k < K_TERMS; ++k) {
                float d = fmaf(Et, ck[k], 1.f);
                acc = fmaf(na2[k], fast_rcp(d), acc);
            }
            ot[j] = acc;
        }
        f32x4 otv = {ot[0], ot[1], ot[2], ot[3]};
        o4[n4 - 1] = otv;
    }
}

extern "C" void kernel_launch(void* const* d_in, const int* in_sizes, int n_in,
                              void* d_out, int out_size, void* d_ws, size_t ws_size,
                              hipStream_t stream) {
    const float* x = (const float*)d_in[0];
    const float* w = (const float*)d_in[1];
    float* out = (float*)d_out;

    int n    = in_sizes[0];   // 2048*4096 = 8388608, divisible by 8
    int n4   = n / 4;         // 2097152 float4's
    int half = n4 / 2;        // 1048576 threads, 8 elements each
    int block = 256;
    int grid  = (half + block - 1) / block;   // 4096 blocks
    quantizationLayer_49563922596433_kernel<<<grid, block, 0, stream>>>(x, w, out, half, n4);
}

// Round 3
// 83.361 us; speedup vs baseline: 1.0591x; 1.0591x over previous
//
#include <hip/hip_runtime.h>

// out[i] = sum_k a[k] * tanh(5*(x[i]+b[k])), k=0..6
// tanh(z) = 1 - 2/(exp(2z)+1)
// exp(10*(x+b_k)) = exp2(SC*x) * exp2(SC*b_k) = E * c_k,  SC = 10*log2(e)
// => out = suma + sum_k (-2*a_k) * rcp(E*c_k + 1)
// ONE exp2 per element (shared across all 7 terms) + 7 rcp.
//
// R3 = revert to the R0 (82.4us-session) memory pattern:
//  - single contiguous float4 stream, 4 elems/thread, plain (cached) ld/st.
//    R2's two-stream + nontemporal variant was neutral-to-negative.
//  - keep vectorized uniform weight loads (f32x4 -> s_load_dwordx4).
// Kernel-side traffic is irreducible: 33.5 MB in + 33.5 MB out = 67 MB
// -> ~10.7 us at 6.3 TB/s achievable. Harness reset (256 MiB ws poison
// fill @ ~43.6 us + restore dispatches) dominates dur_us.

#define K_TERMS 7

typedef float f32x4 __attribute__((ext_vector_type(4)));

__device__ __forceinline__ float fast_exp2(float x) { return __builtin_amdgcn_exp2f(x); }
__device__ __forceinline__ float fast_rcp(float x)  { return __builtin_amdgcn_rcpf(x); }

__global__ __launch_bounds__(256)
void quantizationLayer_49563922596433_kernel(const float* __restrict__ x,
                                             const float* __restrict__ w,
                                             float* __restrict__ out,
                                             int n4) {
    const float SC = 14.4269504088896f; // 10 * log2(e)

    // ---- weight-derived constants: uniform vector loads -> SGPRs ----
    f32x4 w0 = ((const f32x4*)w)[0];   // a0,b0,a1,b1
    f32x4 w1 = ((const f32x4*)w)[1];   // a2,b2,a3,b3
    f32x4 w2 = ((const f32x4*)w)[2];   // a4,b4,a5,b5
    float w3a = w[12], w3b = w[13];    // a6,b6

    float av[K_TERMS] = {w0.x, w0.z, w1.x, w1.z, w2.x, w2.z, w3a};
    float bv[K_TERMS] = {w0.y, w0.w, w1.y, w1.w, w2.y, w2.w, w3b};

    float suma = 0.f;
    float ck[K_TERMS], na2[K_TERMS];
#pragma unroll
    for (int k = 0; k < K_TERMS; ++k) {
        suma  += av[k];
        ck[k]  = fast_exp2(SC * bv[k]);   // exp2 of uniform value
        na2[k] = -2.f * av[k];
    }

    int i = blockIdx.x * blockDim.x + threadIdx.x;
    if (i >= n4) return;

    f32x4 v = ((const f32x4*)x)[i];
    float in[4] = {v.x, v.y, v.z, v.w};
    float o[4];
#pragma unroll
    for (int j = 0; j < 4; ++j) {
        float E   = fast_exp2(in[j] * SC);   // one exp2 per element
        float acc = suma;
#pragma unroll
        for (int k = 0; k < K_TERMS; ++k) {
            float d  = fmaf(E, ck[k], 1.f);  // E*c_k + 1
            acc = fmaf(na2[k], fast_rcp(d), acc);
        }
        o[j] = acc;
    }
    f32x4 ov = {o[0], o[1], o[2], o[3]};
    ((f32x4*)out)[i] = ov;
}

extern "C" void kernel_launch(void* const* d_in, const int* in_sizes, int n_in,
                              void* d_out, int out_size, void* d_ws, size_t ws_size,
                              hipStream_t stream) {
    const float* x = (const float*)d_in[0];
    const float* w = (const float*)d_in[1];
    float* out = (float*)d_out;

    int n  = in_sizes[0];      // 2048*4096 = 8388608, divisible by 4
    int n4 = n / 4;
    int block = 256;
    int grid = (n4 + block - 1) / block;  // 8192 blocks
    quantizationLayer_49563922596433_kernel<<<grid, block, 0, stream>>>(x, w, out, n4);
}